// Round 11
// baseline (101.111 us; speedup 1.0000x reference)
//
#include <hip/hip_runtime.h>
#include <hip/hip_bf16.h>
#include <math.h>

// B=8192, D=1024, H=128, C=16
// out tuple: masked[B*D], mask_norm(0.0), embed_norm(||x||F), x[B*D] -> f32
#define B_ 8192
#define D_ 1024
#define H_ 128
#define C_ 16
#define BD (B_*D_)
#define SUBR 16             // rows per subtile (padded per cond)
#define SLOTS 68            // slots per XCD; grid = 8*68 = 544
#define MAXSUB 150

using bf16x8 = __attribute__((ext_vector_type(8))) __bf16;
using f32x4  = __attribute__((ext_vector_type(4))) float;
typedef unsigned short ushort_t;

// ws layout (bytes):
//   int 16      : nsub[8]
//   int 32      : subtbl[8][150][3] (cond, prow0, end)
//   int 8192    : sidx[8448]  padded sorted-pos -> orig row  (byte 32768)
//   131072      : ep[16] f32
//   262144      : w1s bf16 (4 MiB)  [cond][jf8][ks32][lane64][8]
//   4456448     : w2s bf16 (4 MiB)  [cond][jf64][ks4][lane64][8]

__device__ inline bf16x8 cvt8(float4 a, float4 b) {
    bf16x8 r;
    r[0] = (__bf16)a.x; r[1] = (__bf16)a.y; r[2] = (__bf16)a.z; r[3] = (__bf16)a.w;
    r[4] = (__bf16)b.x; r[5] = (__bf16)b.y; r[6] = (__bf16)b.z; r[7] = (__bf16)b.w;
    return r;
}
__device__ inline unsigned pack2(float a, float b) {
    unsigned ua = __builtin_bit_cast(unsigned short, (__bf16)a);
    unsigned ub = __builtin_bit_cast(unsigned short, (__bf16)b);
    return ua | (ub << 16);
}

// ---- histogram + padded per-XCD subtile table + scatter; zeroes ep ----
__global__ __launch_bounds__(1024) void k_sort(const int* __restrict__ c,
                                               int* __restrict__ w,
                                               float* __restrict__ ep) {
    __shared__ int hist[C_], base[C_];
    int tid = threadIdx.x;
    if (tid < C_) { hist[tid] = 0; ep[tid] = 0.0f; }
    __syncthreads();
    int myc[8];
#pragma unroll
    for (int i = 0; i < 8; ++i) {
        myc[i] = c[tid * 8 + i];
        atomicAdd(&hist[myc[i]], 1);
    }
    __syncthreads();
    if (tid == 0) {
        int off = 0; int ns[8] = {0,0,0,0,0,0,0,0};
        for (int cc = 0; cc < C_; ++cc) {
            int cnt = hist[cc]; base[cc] = off;
            int nt = (cnt + SUBR - 1) >> 4;
            int xcd = cc >> 1;                 // 2 conds/XCD -> weights L2-resident
            for (int t = 0; t < nt; ++t) {
                int s = ns[xcd]++;
                int* e = &w[32 + (xcd * MAXSUB + s) * 3];
                e[0] = cc; e[1] = off + t * SUBR; e[2] = off + cnt;
            }
            off += nt * SUBR;              // padded to 16-row alignment
        }
        for (int xx = 0; xx < 8; ++xx) w[16 + xx] = ns[xx];
    }
    __syncthreads();
#pragma unroll
    for (int i = 0; i < 8; ++i) {
        int pos = atomicAdd(&base[myc[i]], 1);
        w[8192 + pos] = tid * 8 + i;       // sidx (padded positions)
    }
}

// ---- prep: W1,W2 -> bf16 fragment-ordered streams (weights only) ----
__global__ __launch_bounds__(256) void k_prepw(const float* __restrict__ W1f,
                                               const float* __restrict__ W2f,
                                               __bf16* __restrict__ w1s,
                                               __bf16* __restrict__ w2s) {
    int bid = blockIdx.x, tid = threadIdx.x;
    if (bid < 128) {                        // W1 -> w1s [cond][jf8][ks32][lane]
#pragma unroll
        for (int u = 0; u < 8; ++u) {
            int g = bid * 2048 + u * 256 + tid;
            int cond = g >> 14, jf = (g >> 11) & 7, ks = (g >> 6) & 31, lam = g & 63;
            int l15 = lam & 15, kg = lam >> 4;
            const float* src = W1f + ((size_t)cond * 128 + jf * 16 + l15) * 1024 + ks * 32 + kg * 8;
            *(bf16x8*)(w1s + (size_t)g * 8) = cvt8(*(const float4*)src, *(const float4*)(src + 4));
        }
    } else {                                // W2 -> w2s [cond][jf64][ks4][lane]
        int wb = bid - 128;
#pragma unroll
        for (int u = 0; u < 8; ++u) {
            int g = wb * 2048 + u * 256 + tid;
            int cond = g >> 14, jf = (g >> 8) & 63, ks = (g >> 6) & 3, lam = g & 63;
            int l15 = lam & 15, kg = lam >> 4;
            const float* src = W2f + ((size_t)cond * 1024 + jf * 16 + l15) * 128 + ks * 32 + kg * 8;
            *(bf16x8*)(w2s + (size_t)g * 8) = cvt8(*(const float4*)src, *(const float4*)(src + 4));
        }
    }
}

// ---- fused: x gather+convert + MLP + normalize + xcopy + ||x||^2 ----
__global__ __launch_bounds__(512, 8) void k_f(const float* __restrict__ x,
                                              const __bf16* __restrict__ w1s,
                                              const __bf16* __restrict__ w2s,
                                              const float* __restrict__ b1f,
                                              const float* __restrict__ b2f,
                                              const int* __restrict__ wsi,
                                              float* __restrict__ out,
                                              float* __restrict__ ep) {
    int xcd = blockIdx.x & 7, slot0 = blockIdx.x >> 3;
    int nsub = wsi[16 + xcd];
    const int* sidx = wsi + 8192;

    __shared__ ulong2 xot_raw[2048];        // 32 KB: x frags -> bf16 out-tile
    __shared__ ushort_t Hs[16 * 128];       // 4 KB h tile (slot-XOR swizzled)
    __shared__ float sqs[16 * 8];
    char* ldsx = (char*)xot_raw;
    unsigned* Ot32 = (unsigned*)xot_raw;    // [rowpair8][col1024] u32 = rows (2r,2r+1)

    int tid = threadIdx.x, wv = tid >> 6, lane = tid & 63, l15 = lane & 15, kg = lane >> 4;
    int sr = tid & 15, sks = tid >> 4;      // staging: row, ks-chunk
    float xsq = 0.0f;

    for (int si = slot0; si < nsub; si += SLOTS) {
        const int* e = wsi + 32 + (xcd * MAXSUB + si) * 3;
        int cond = e[0], prow0 = e[1], end = e[2];

        // ---- stage x: gather 16 rows f32, convert to bf16 fragments; xcopy + xsq ----
        {
            int pr = prow0 + sr;
            bool valid = pr < end;
            int orow = sidx[valid ? pr : (end - 1)];
            const float* xs = x + (size_t)orow * D_ + sks * 32;
            float* xc = out + (size_t)BD + 2 + (size_t)orow * D_ + sks * 32;
            char* dst = ldsx + sks * 1024 + sr * 16;
#pragma unroll
            for (int h = 0; h < 2; ++h) {
                float4 f0 = *(const float4*)(xs + h * 16);
                float4 f1 = *(const float4*)(xs + h * 16 + 4);
                float4 f2 = *(const float4*)(xs + h * 16 + 8);
                float4 f3 = *(const float4*)(xs + h * 16 + 12);
                *(bf16x8*)(dst + (h * 2) * 256)     = cvt8(f0, f1);
                *(bf16x8*)(dst + (h * 2 + 1) * 256) = cvt8(f2, f3);
                if (valid) {
                    float2* xo = (float2*)(xc + h * 16);
                    xo[0] = make_float2(f0.x, f0.y); xo[1] = make_float2(f0.z, f0.w);
                    xo[2] = make_float2(f1.x, f1.y); xo[3] = make_float2(f1.z, f1.w);
                    xo[4] = make_float2(f2.x, f2.y); xo[5] = make_float2(f2.z, f2.w);
                    xo[6] = make_float2(f3.x, f3.y); xo[7] = make_float2(f3.z, f3.w);
                    xsq += f0.x*f0.x + f0.y*f0.y + f0.z*f0.z + f0.w*f0.w
                         + f1.x*f1.x + f1.y*f1.y + f1.z*f1.z + f1.w*f1.w
                         + f2.x*f2.x + f2.y*f2.y + f2.z*f2.z + f2.w*f2.w
                         + f3.x*f3.x + f3.y*f3.y + f3.z*f3.z + f3.w*f3.w;
                }
            }
        }
        __syncthreads();

        // ---- L1: wave wv computes h cols [wv*16,+16) for 16 rows ----
        const char* bA = (const char*)w1s + (size_t)cond * 262144 + wv * 32768 + lane * 16;
        f32x4 acc = {};
#pragma unroll 8
        for (int ks = 0; ks < 32; ++ks) {
            bf16x8 b  = *(const bf16x8*)(bA + ks * 1024);
            bf16x8 x0 = *(const bf16x8*)(ldsx + ks * 1024 + lane * 16);
            acc = __builtin_amdgcn_mfma_f32_16x16x32_bf16(x0, b, acc, 0, 0, 0);
        }
        __syncthreads();   // all waves done reading x region

        // ---- h + b1 -> Hs (swizzled bf16) ----
        {
            int j0 = wv * 16 + l15;
            float bias = b1f[cond * 128 + j0];
            int sl0 = j0 >> 3, jb = j0 & 7;
#pragma unroll
            for (int v = 0; v < 4; ++v) {
                int r0 = kg * 4 + v;
                __bf16 h0 = (__bf16)(acc[v] + bias);
                Hs[r0 * 128 + ((sl0 ^ (r0 & 7)) * 8) + jb] = __builtin_bit_cast(ushort_t, h0);
            }
        }
        __syncthreads();

        // ---- pa fragments ----
        bf16x8 pa[4];
#pragma unroll
        for (int i = 0; i < 4; ++i)
            pa[i] = *(const bf16x8*)(Hs + l15 * 128 + (((i * 4 + kg) ^ (l15 & 7)) * 8));

        // ---- L2: wave wv owns out cols [wv*128,+128); results -> LDS out-tile ----
        const char* w2b = (const char*)w2s + (size_t)cond * 262144 + wv * 32768 + lane * 16;
        float sq[4] = {0.f, 0.f, 0.f, 0.f};
        unsigned cswz = (unsigned)((kg & 1) << 4);
#pragma unroll
        for (int f = 0; f < 8; ++f) {
            bf16x8 q0 = *(const bf16x8*)(w2b + f * 4096);
            bf16x8 q1 = *(const bf16x8*)(w2b + f * 4096 + 1024);
            bf16x8 q2 = *(const bf16x8*)(w2b + f * 4096 + 2048);
            bf16x8 q3 = *(const bf16x8*)(w2b + f * 4096 + 3072);
            f32x4 c0 = {};
            c0 = __builtin_amdgcn_mfma_f32_16x16x32_bf16(pa[0], q0, c0, 0, 0, 0);
            c0 = __builtin_amdgcn_mfma_f32_16x16x32_bf16(pa[1], q1, c0, 0, 0, 0);
            c0 = __builtin_amdgcn_mfma_f32_16x16x32_bf16(pa[2], q2, c0, 0, 0, 0);
            c0 = __builtin_amdgcn_mfma_f32_16x16x32_bf16(pa[3], q3, c0, 0, 0, 0);
            int jg = (wv * 8 + f) * 16 + l15;
            float bias = b2f[cond * 1024 + jg];
            float t0 = c0[0] + bias, t1 = c0[1] + bias, t2 = c0[2] + bias, t3 = c0[3] + bias;
            sq[0] += t0*t0; sq[1] += t1*t1; sq[2] += t2*t2; sq[3] += t3*t3;
            unsigned jc = (unsigned)jg ^ cswz;
            Ot32[(kg * 2    ) * 1024 + jc] = pack2(t0, t1);
            Ot32[(kg * 2 + 1) * 1024 + jc] = pack2(t2, t3);
        }
        // per-row sums: shfl over l15 -> LDS across waves
#pragma unroll
        for (int v = 0; v < 4; ++v) {
            float s = sq[v];
            s += __shfl_xor(s, 1); s += __shfl_xor(s, 2);
            s += __shfl_xor(s, 4); s += __shfl_xor(s, 8);
            if (l15 == 0) sqs[(kg * 4 + v) * 8 + wv] = s;
        }
        __syncthreads();

        // ---- fused normalize + fully-coalesced store: wave wv -> rows [wv*2,+2) ----
#pragma unroll
        for (int rr = 0; rr < 2; ++rr) {
            int r = wv * 2 + rr;
            int pr = prow0 + r;
            if (pr < end) {
                int orow = sidx[pr];
                float s = sqs[r*8+0] + sqs[r*8+1] + sqs[r*8+2] + sqs[r*8+3]
                        + sqs[r*8+4] + sqs[r*8+5] + sqs[r*8+6] + sqs[r*8+7];
                float inv = 1.0f / (sqrtf(s) + 1e-10f);
                int hi = (r & 1) * 16;
                unsigned rswz = (unsigned)(((r >> 2) & 1) << 4);
                const unsigned* base = Ot32 + (r >> 1) * 1024;
                float4* go = (float4*)(out + (size_t)orow * D_);
#pragma unroll
                for (int it = 0; it < 4; ++it) {
                    unsigned cu = (unsigned)(lane * 4 + it * 256) ^ rswz;
                    uint4 u = *(const uint4*)(base + cu);
                    float4 v;
                    v.x = (float)__builtin_bit_cast(__bf16, (ushort_t)(u.x >> hi)) * inv;
                    v.y = (float)__builtin_bit_cast(__bf16, (ushort_t)(u.y >> hi)) * inv;
                    v.z = (float)__builtin_bit_cast(__bf16, (ushort_t)(u.z >> hi)) * inv;
                    v.w = (float)__builtin_bit_cast(__bf16, (ushort_t)(u.w >> hi)) * inv;
                    go[lane + it * 64] = v;
                }
            }
        }
        __syncthreads();   // protect LDS for next subtile
    }

    // ---- ||x||^2 block reduction -> 16 buckets ----
    float s = xsq;
    s += __shfl_xor(s, 1);  s += __shfl_xor(s, 2);  s += __shfl_xor(s, 4);
    s += __shfl_xor(s, 8);  s += __shfl_xor(s, 16); s += __shfl_xor(s, 32);
    if (lane == 0) sqs[wv] = s;
    __syncthreads();
    if (tid == 0) {
        float t = sqs[0] + sqs[1] + sqs[2] + sqs[3] + sqs[4] + sqs[5] + sqs[6] + sqs[7];
        atomicAdd(&ep[blockIdx.x & 15], t);
    }
}

__global__ void k_fin(const float* __restrict__ ep, float* __restrict__ out) {
    float s = 0.0f;
#pragma unroll
    for (int i = 0; i < 16; ++i) s += ep[i];
    out[BD] = 0.0f;
    out[BD + 1] = sqrtf(s);
}

extern "C" void kernel_launch(void* const* d_in, const int* in_sizes, int n_in,
                              void* d_out, int out_size, void* d_ws, size_t ws_size,
                              hipStream_t stream) {
    const float* x  = (const float*)d_in[0];
    const int*   c  = (const int*)d_in[1];
    const float* W1 = (const float*)d_in[2];
    const float* b1 = (const float*)d_in[3];
    const float* W2 = (const float*)d_in[4];
    const float* b2 = (const float*)d_in[5];
    float* out = (float*)d_out;
    char* ws = (char*)d_ws;
    int* wsi = (int*)ws;
    float* ep   = (float*)(ws + 131072);
    __bf16* w1s = (__bf16*)(ws + 262144);
    __bf16* w2s = (__bf16*)(ws + 4456448);

    k_sort<<<1, 1024, 0, stream>>>(c, wsi, ep);
    k_prepw<<<256, 256, 0, stream>>>(W1, W2, w1s, w2s);
    k_f<<<8 * SLOTS, 512, 0, stream>>>(x, w1s, w2s, b1, b2, wsi, out, ep);
    k_fin<<<1, 1, 0, stream>>>(ep, out);
}

// Round 12
// 86.369 us; speedup vs baseline: 1.1707x; 1.1707x over previous
//
#include <hip/hip_runtime.h>
#include <hip/hip_bf16.h>
#include <math.h>

// B=8192, D=1024, H=128, C=16
// out tuple: masked[B*D], mask_norm(0.0), embed_norm(||x||F), x[B*D] -> f32
#define B_ 8192
#define D_ 1024
#define H_ 128
#define C_ 16
#define BD (B_*D_)
#define SUBR 16             // rows per subtile (padded per cond)
#define SLOTS 68            // slots per XCD; grid = 8*68 = 544
#define MAXSUB 150

using bf16x8 = __attribute__((ext_vector_type(8))) __bf16;
using f32x4  = __attribute__((ext_vector_type(4))) float;
typedef unsigned short ushort_t;

// ws layout (bytes):
//   int 16      : nsub[8]
//   int 32      : subtbl[8][150][3] (cond, prow0, end)
//   int 8192    : sidx[8448]  padded sorted-pos -> orig row  (byte 32768)
//   131072      : ep[16] f32
//   262144      : w1s bf16 (4 MiB)  [cond][jf8][ks32][lane64][8]
//   4456448     : w2s bf16 (4 MiB)  [cond][jf64][ks4][lane64][8]

__device__ inline bf16x8 cvt8(float4 a, float4 b) {
    bf16x8 r;
    r[0] = (__bf16)a.x; r[1] = (__bf16)a.y; r[2] = (__bf16)a.z; r[3] = (__bf16)a.w;
    r[4] = (__bf16)b.x; r[5] = (__bf16)b.y; r[6] = (__bf16)b.z; r[7] = (__bf16)b.w;
    return r;
}
__device__ inline unsigned pack2(float a, float b) {
    unsigned ua = __builtin_bit_cast(unsigned short, (__bf16)a);
    unsigned ub = __builtin_bit_cast(unsigned short, (__bf16)b);
    return ua | (ub << 16);
}

// ---- histogram + padded per-XCD subtile table + scatter; zeroes ep ----
__global__ __launch_bounds__(1024) void k_sort(const int* __restrict__ c,
                                               int* __restrict__ w,
                                               float* __restrict__ ep) {
    __shared__ int hist[C_], base[C_];
    int tid = threadIdx.x;
    if (tid < C_) { hist[tid] = 0; ep[tid] = 0.0f; }
    __syncthreads();
    int myc[8];
#pragma unroll
    for (int i = 0; i < 8; ++i) {
        myc[i] = c[tid * 8 + i];
        atomicAdd(&hist[myc[i]], 1);
    }
    __syncthreads();
    if (tid == 0) {
        int off = 0; int ns[8] = {0,0,0,0,0,0,0,0};
        for (int cc = 0; cc < C_; ++cc) {
            int cnt = hist[cc]; base[cc] = off;
            int nt = (cnt + SUBR - 1) >> 4;
            int xcd = cc >> 1;                 // 2 conds/XCD -> weights L2-resident
            for (int t = 0; t < nt; ++t) {
                int s = ns[xcd]++;
                int* e = &w[32 + (xcd * MAXSUB + s) * 3];
                e[0] = cc; e[1] = off + t * SUBR; e[2] = off + cnt;
            }
            off += nt * SUBR;              // padded to 16-row alignment
        }
        for (int xx = 0; xx < 8; ++xx) w[16 + xx] = ns[xx];
    }
    __syncthreads();
#pragma unroll
    for (int i = 0; i < 8; ++i) {
        int pos = atomicAdd(&base[myc[i]], 1);
        w[8192 + pos] = tid * 8 + i;       // sidx (padded positions)
    }
}

// ---- prep: W1,W2 -> bf16 fragment-ordered streams (weights only) ----
__global__ __launch_bounds__(256) void k_prepw(const float* __restrict__ W1f,
                                               const float* __restrict__ W2f,
                                               __bf16* __restrict__ w1s,
                                               __bf16* __restrict__ w2s) {
    int bid = blockIdx.x, tid = threadIdx.x;
    if (bid < 128) {                        // W1 -> w1s [cond][jf8][ks32][lane]
#pragma unroll
        for (int u = 0; u < 8; ++u) {
            int g = bid * 2048 + u * 256 + tid;
            int cond = g >> 14, jf = (g >> 11) & 7, ks = (g >> 6) & 31, lam = g & 63;
            int l15 = lam & 15, kg = lam >> 4;
            const float* src = W1f + ((size_t)cond * 128 + jf * 16 + l15) * 1024 + ks * 32 + kg * 8;
            *(bf16x8*)(w1s + (size_t)g * 8) = cvt8(*(const float4*)src, *(const float4*)(src + 4));
        }
    } else {                                // W2 -> w2s [cond][jf64][ks4][lane]
        int wb = bid - 128;
#pragma unroll
        for (int u = 0; u < 8; ++u) {
            int g = wb * 2048 + u * 256 + tid;
            int cond = g >> 14, jf = (g >> 8) & 63, ks = (g >> 6) & 3, lam = g & 63;
            int l15 = lam & 15, kg = lam >> 4;
            const float* src = W2f + ((size_t)cond * 1024 + jf * 16 + l15) * 128 + ks * 32 + kg * 8;
            *(bf16x8*)(w2s + (size_t)g * 8) = cvt8(*(const float4*)src, *(const float4*)(src + 4));
        }
    }
}

// ---- fused: x gather+convert + MLP + normalize + xcopy + ||x||^2 ----
// Register-dieted for <=64 VGPR @ 4 blocks/CU (32 waves/CU).
__global__ __launch_bounds__(512, 4) void k_f(const float* __restrict__ x,
                                              const __bf16* __restrict__ w1s,
                                              const __bf16* __restrict__ w2s,
                                              const float* __restrict__ b1f,
                                              const float* __restrict__ b2f,
                                              const int* __restrict__ wsi,
                                              float* __restrict__ out,
                                              float* __restrict__ ep) {
    int xcd = blockIdx.x & 7, slot0 = blockIdx.x >> 3;
    int nsub = wsi[16 + xcd];
    const int* sidx = wsi + 8192;

    __shared__ ulong2 xot_raw[2048];        // 32 KB: x frags -> bf16 out-tile
    __shared__ ushort_t Hs[16 * 128];       // 4 KB h tile (slot-XOR swizzled)
    __shared__ float sqs[16 * 8];
    char* ldsx = (char*)xot_raw;
    unsigned* Ot32 = (unsigned*)xot_raw;    // [rowpair8][col1024] u32 = rows (2r,2r+1)

    int tid = threadIdx.x, wv = tid >> 6, lane = tid & 63, l15 = lane & 15, kg = lane >> 4;
    int sr = tid & 15, sks = tid >> 4;      // staging: row, ks-chunk
    float xsq = 0.0f;

    for (int si = slot0; si < nsub; si += SLOTS) {
        const int* e = wsi + 32 + (xcd * MAXSUB + si) * 3;
        int cond = e[0], prow0 = e[1], end = e[2];

        // ---- stage x: gather 16 rows f32, convert to bf16 fragments; xcopy + xsq ----
        {
            int pr = prow0 + sr;
            bool valid = pr < end;
            int orow = sidx[valid ? pr : (end - 1)];
            const float* xs = x + (size_t)orow * D_ + sks * 32;
            float* xc = out + (size_t)BD + 2 + (size_t)orow * D_ + sks * 32;
            char* dst = ldsx + sks * 1024 + sr * 16;
#pragma unroll 1
            for (int h = 0; h < 2; ++h) {
                float4 f0 = *(const float4*)(xs + h * 16);
                float4 f1 = *(const float4*)(xs + h * 16 + 4);
                float4 f2 = *(const float4*)(xs + h * 16 + 8);
                float4 f3 = *(const float4*)(xs + h * 16 + 12);
                *(bf16x8*)(dst + (h * 2) * 256)     = cvt8(f0, f1);
                *(bf16x8*)(dst + (h * 2 + 1) * 256) = cvt8(f2, f3);
                if (valid) {
                    float2* xo = (float2*)(xc + h * 16);
                    xo[0] = make_float2(f0.x, f0.y); xo[1] = make_float2(f0.z, f0.w);
                    xo[2] = make_float2(f1.x, f1.y); xo[3] = make_float2(f1.z, f1.w);
                    xo[4] = make_float2(f2.x, f2.y); xo[5] = make_float2(f2.z, f2.w);
                    xo[6] = make_float2(f3.x, f3.y); xo[7] = make_float2(f3.z, f3.w);
                    xsq += f0.x*f0.x + f0.y*f0.y + f0.z*f0.z + f0.w*f0.w
                         + f1.x*f1.x + f1.y*f1.y + f1.z*f1.z + f1.w*f1.w
                         + f2.x*f2.x + f2.y*f2.y + f2.z*f2.z + f2.w*f2.w
                         + f3.x*f3.x + f3.y*f3.y + f3.z*f3.z + f3.w*f3.w;
                }
            }
        }
        __syncthreads();

        // ---- L1: wave wv computes h cols [wv*16,+16) for 16 rows ----
        const char* bA = (const char*)w1s + (size_t)cond * 262144 + wv * 32768 + lane * 16;
        f32x4 acc = {};
#pragma unroll 2
        for (int ks = 0; ks < 32; ++ks) {
            bf16x8 b  = *(const bf16x8*)(bA + ks * 1024);
            bf16x8 x0 = *(const bf16x8*)(ldsx + ks * 1024 + lane * 16);
            acc = __builtin_amdgcn_mfma_f32_16x16x32_bf16(x0, b, acc, 0, 0, 0);
        }
        __syncthreads();   // all waves done reading x region

        // ---- h + b1 -> Hs (swizzled bf16) ----
        {
            int j0 = wv * 16 + l15;
            float bias = b1f[cond * 128 + j0];
            int sl0 = j0 >> 3, jb = j0 & 7;
#pragma unroll
            for (int v = 0; v < 4; ++v) {
                int r0 = kg * 4 + v;
                __bf16 h0 = (__bf16)(acc[v] + bias);
                Hs[r0 * 128 + ((sl0 ^ (r0 & 7)) * 8) + jb] = __builtin_bit_cast(ushort_t, h0);
            }
        }
        __syncthreads();

        // ---- pa fragments ----
        bf16x8 pa[4];
#pragma unroll
        for (int i = 0; i < 4; ++i)
            pa[i] = *(const bf16x8*)(Hs + l15 * 128 + (((i * 4 + kg) ^ (l15 & 7)) * 8));

        // ---- L2: wave wv owns out cols [wv*128,+128); sequential q->MFMA, low regs ----
        const char* w2b = (const char*)w2s + (size_t)cond * 262144 + wv * 32768 + lane * 16;
        float sq[4] = {0.f, 0.f, 0.f, 0.f};
        unsigned cswz = (unsigned)((kg & 1) << 4);
#pragma unroll 1
        for (int f = 0; f < 8; ++f) {
            const char* wb = w2b + f * 4096;
            f32x4 c0 = {};
            bf16x8 q;
            q  = *(const bf16x8*)(wb);
            c0 = __builtin_amdgcn_mfma_f32_16x16x32_bf16(pa[0], q, c0, 0, 0, 0);
            q  = *(const bf16x8*)(wb + 1024);
            c0 = __builtin_amdgcn_mfma_f32_16x16x32_bf16(pa[1], q, c0, 0, 0, 0);
            q  = *(const bf16x8*)(wb + 2048);
            c0 = __builtin_amdgcn_mfma_f32_16x16x32_bf16(pa[2], q, c0, 0, 0, 0);
            q  = *(const bf16x8*)(wb + 3072);
            c0 = __builtin_amdgcn_mfma_f32_16x16x32_bf16(pa[3], q, c0, 0, 0, 0);
            int jg = (wv * 8 + f) * 16 + l15;
            float bias = b2f[cond * 1024 + jg];
            float t0 = c0[0] + bias, t1 = c0[1] + bias, t2 = c0[2] + bias, t3 = c0[3] + bias;
            sq[0] += t0*t0; sq[1] += t1*t1; sq[2] += t2*t2; sq[3] += t3*t3;
            unsigned jc = (unsigned)jg ^ cswz;
            Ot32[(kg * 2    ) * 1024 + jc] = pack2(t0, t1);
            Ot32[(kg * 2 + 1) * 1024 + jc] = pack2(t2, t3);
        }
        // per-row sums: shfl over l15 -> LDS across waves
#pragma unroll
        for (int v = 0; v < 4; ++v) {
            float s = sq[v];
            s += __shfl_xor(s, 1); s += __shfl_xor(s, 2);
            s += __shfl_xor(s, 4); s += __shfl_xor(s, 8);
            if (l15 == 0) sqs[(kg * 4 + v) * 8 + wv] = s;
        }
        __syncthreads();

        // ---- fused normalize + fully-coalesced store: wave wv -> rows [wv*2,+2) ----
#pragma unroll 1
        for (int rr = 0; rr < 2; ++rr) {
            int r = wv * 2 + rr;
            int pr = prow0 + r;
            if (pr < end) {
                int orow = sidx[pr];
                float s = sqs[r*8+0] + sqs[r*8+1] + sqs[r*8+2] + sqs[r*8+3]
                        + sqs[r*8+4] + sqs[r*8+5] + sqs[r*8+6] + sqs[r*8+7];
                float inv = 1.0f / (sqrtf(s) + 1e-10f);
                int hi = (r & 1) * 16;
                unsigned rswz = (unsigned)(((r >> 2) & 1) << 4);
                const unsigned* base = Ot32 + (r >> 1) * 1024;
                float4* go = (float4*)(out + (size_t)orow * D_);
#pragma unroll
                for (int it = 0; it < 4; ++it) {
                    unsigned cu = (unsigned)(lane * 4 + it * 256) ^ rswz;
                    uint4 u = *(const uint4*)(base + cu);
                    float4 v;
                    v.x = (float)__builtin_bit_cast(__bf16, (ushort_t)(u.x >> hi)) * inv;
                    v.y = (float)__builtin_bit_cast(__bf16, (ushort_t)(u.y >> hi)) * inv;
                    v.z = (float)__builtin_bit_cast(__bf16, (ushort_t)(u.z >> hi)) * inv;
                    v.w = (float)__builtin_bit_cast(__bf16, (ushort_t)(u.w >> hi)) * inv;
                    go[lane + it * 64] = v;
                }
            }
        }
        __syncthreads();   // protect LDS for next subtile
    }

    // ---- ||x||^2 block reduction -> 16 buckets ----
    float s = xsq;
    s += __shfl_xor(s, 1);  s += __shfl_xor(s, 2);  s += __shfl_xor(s, 4);
    s += __shfl_xor(s, 8);  s += __shfl_xor(s, 16); s += __shfl_xor(s, 32);
    if (lane == 0) sqs[wv] = s;
    __syncthreads();
    if (tid == 0) {
        float t = sqs[0] + sqs[1] + sqs[2] + sqs[3] + sqs[4] + sqs[5] + sqs[6] + sqs[7];
        atomicAdd(&ep[blockIdx.x & 15], t);
    }
}

__global__ void k_fin(const float* __restrict__ ep, float* __restrict__ out) {
    float s = 0.0f;
#pragma unroll
    for (int i = 0; i < 16; ++i) s += ep[i];
    out[BD] = 0.0f;
    out[BD + 1] = sqrtf(s);
}

extern "C" void kernel_launch(void* const* d_in, const int* in_sizes, int n_in,
                              void* d_out, int out_size, void* d_ws, size_t ws_size,
                              hipStream_t stream) {
    const float* x  = (const float*)d_in[0];
    const int*   c  = (const int*)d_in[1];
    const float* W1 = (const float*)d_in[2];
    const float* b1 = (const float*)d_in[3];
    const float* W2 = (const float*)d_in[4];
    const float* b2 = (const float*)d_in[5];
    float* out = (float*)d_out;
    char* ws = (char*)d_ws;
    int* wsi = (int*)ws;
    float* ep   = (float*)(ws + 131072);
    __bf16* w1s = (__bf16*)(ws + 262144);
    __bf16* w2s = (__bf16*)(ws + 4456448);

    k_sort<<<1, 1024, 0, stream>>>(c, wsi, ep);
    k_prepw<<<256, 256, 0, stream>>>(W1, W2, w1s, w2s);
    k_f<<<8 * SLOTS, 512, 0, stream>>>(x, w1s, w2s, b1, b2, wsi, out, ep);
    k_fin<<<1, 1, 0, stream>>>(ep, out);
}

// Round 13
// 76.570 us; speedup vs baseline: 1.3205x; 1.1280x over previous
//
#include <hip/hip_runtime.h>
#include <hip/hip_bf16.h>
#include <math.h>

// B=8192, D=1024, H=128, C=16
// out tuple: masked[B*D], mask_norm(0.0), embed_norm(||x||F), x[B*D] -> f32
#define B_ 8192
#define D_ 1024
#define H_ 128
#define C_ 16
#define BD (B_*D_)
#define SUBR 16             // rows per subtile (padded per cond)
#define SLOTS 68            // slots per XCD; grid = 8*68 = 544
#define MAXSUB 150
#define GRID_F (8 * SLOTS)

using bf16x8 = __attribute__((ext_vector_type(8))) __bf16;
using f32x4  = __attribute__((ext_vector_type(4))) float;
typedef unsigned short ushort_t;

// ws layout (bytes):
//   int 16      : nsub[8]
//   int 24      : done counter
//   int 32      : subtbl[8][150][3] (cond, prow0, end)
//   int 8192    : sidx[8448]  padded sorted-pos -> orig row  (byte 32768)
//   131072      : ep[16] f32
//   262144      : w1s bf16 (4 MiB)  [cond][jf8][ks32][lane64][8]
//   4456448     : w2s bf16 (4 MiB)  [cond][jf64][ks4][lane64][8]

__device__ inline bf16x8 cvt8(float4 a, float4 b) {
    bf16x8 r;
    r[0] = (__bf16)a.x; r[1] = (__bf16)a.y; r[2] = (__bf16)a.z; r[3] = (__bf16)a.w;
    r[4] = (__bf16)b.x; r[5] = (__bf16)b.y; r[6] = (__bf16)b.z; r[7] = (__bf16)b.w;
    return r;
}
__device__ inline unsigned pack2(float a, float b) {
    unsigned ua = __builtin_bit_cast(unsigned short, (__bf16)a);
    unsigned ub = __builtin_bit_cast(unsigned short, (__bf16)b);
    return ua | (ub << 16);
}

// ---- prep: blocks 0..127 W1->w1s, 128..255 W2->w2s, block 256: sort/table/scatter ----
__global__ __launch_bounds__(256) void k_prep(const float* __restrict__ W1f,
                                              const float* __restrict__ W2f,
                                              const int* __restrict__ c,
                                              __bf16* __restrict__ w1s,
                                              __bf16* __restrict__ w2s,
                                              int* __restrict__ w,
                                              float* __restrict__ ep) {
    int bid = blockIdx.x, tid = threadIdx.x;
    if (bid < 128) {                        // W1 -> w1s [cond][jf8][ks32][lane]
#pragma unroll
        for (int u = 0; u < 8; ++u) {
            int g = bid * 2048 + u * 256 + tid;
            int cond = g >> 14, jf = (g >> 11) & 7, ks = (g >> 6) & 31, lam = g & 63;
            int l15 = lam & 15, kg = lam >> 4;
            const float* src = W1f + ((size_t)cond * 128 + jf * 16 + l15) * 1024 + ks * 32 + kg * 8;
            *(bf16x8*)(w1s + (size_t)g * 8) = cvt8(*(const float4*)src, *(const float4*)(src + 4));
        }
    } else if (bid < 256) {                 // W2 -> w2s [cond][jf64][ks4][lane]
        int wb = bid - 128;
#pragma unroll
        for (int u = 0; u < 8; ++u) {
            int g = wb * 2048 + u * 256 + tid;
            int cond = g >> 14, jf = (g >> 8) & 63, ks = (g >> 6) & 3, lam = g & 63;
            int l15 = lam & 15, kg = lam >> 4;
            const float* src = W2f + ((size_t)cond * 1024 + jf * 16 + l15) * 128 + ks * 32 + kg * 8;
            *(bf16x8*)(w2s + (size_t)g * 8) = cvt8(*(const float4*)src, *(const float4*)(src + 4));
        }
    } else {                                // sort: hist + padded table + scatter; zero ep/done
        __shared__ int hist[C_], base[C_], poff[C_], nt[C_];
        if (tid < C_) { hist[tid] = 0; ep[tid] = 0.0f; }
        if (tid == 0) w[24] = 0;            // done counter
        __syncthreads();
        for (int i = tid; i < B_; i += 256) atomicAdd(&hist[c[i]], 1);
        __syncthreads();
        if (tid == 0) {
            int off = 0;
            for (int cc = 0; cc < C_; ++cc) {
                nt[cc] = (hist[cc] + SUBR - 1) >> 4;
                poff[cc] = off;
                base[cc] = off;
                off += nt[cc] * SUBR;       // padded to 16-row alignment
            }
        }
        __syncthreads();
        if (tid < C_) {                     // per-cond parallel table build
            int cc = tid, xcd = cc >> 1;
            int s0 = (cc & 1) ? nt[cc - 1] : 0;
            int end = poff[cc] + hist[cc];
            for (int t = 0; t < nt[cc]; ++t) {
                int* e = &w[32 + (xcd * MAXSUB + s0 + t) * 3];
                e[0] = cc; e[1] = poff[cc] + t * SUBR; e[2] = end;
            }
            if ((cc & 1) == 0) w[16 + xcd] = nt[cc] + nt[cc + 1];
        }
        __syncthreads();
        for (int i = tid; i < B_; i += 256) {
            int pos = atomicAdd(&base[c[i]], 1);
            w[8192 + pos] = i;              // sidx (padded positions)
        }
    }
}

// ---- fused: x gather+convert + MLP + normalize + xcopy + ||x||^2 + finalize ----
__global__ __launch_bounds__(512, 4) void k_f(const float* __restrict__ x,
                                              const __bf16* __restrict__ w1s,
                                              const __bf16* __restrict__ w2s,
                                              const float* __restrict__ b1f,
                                              const float* __restrict__ b2f,
                                              int* __restrict__ wsi,
                                              float* __restrict__ out,
                                              float* __restrict__ ep) {
    int xcd = blockIdx.x & 7, slot0 = blockIdx.x >> 3;
    int nsub = wsi[16 + xcd];
    const int* sidx = wsi + 8192;

    __shared__ ulong2 xot_raw[2048];        // 32 KB: x frags -> bf16 out-tile
    __shared__ ushort_t Hs[16 * 128];       // 4 KB h tile (slot-XOR swizzled)
    __shared__ float sqs[16 * 8];
    char* ldsx = (char*)xot_raw;
    unsigned* Ot32 = (unsigned*)xot_raw;    // [rowpair8][col1024] u32 = rows (2r,2r+1)

    int tid = threadIdx.x, wv = tid >> 6, lane = tid & 63, l15 = lane & 15, kg = lane >> 4;
    int sr = wv * 2 + (lane >> 5);          // staging row: wave covers rows 2wv,2wv+1
    int cg = lane & 31;                     // 32 lanes cover a row contiguously
    int skg = cg & 3, skb = cg >> 2;
    float xsq = 0.0f;

    for (int si = slot0; si < nsub; si += SLOTS) {
        const int* e = wsi + 32 + (xcd * MAXSUB + si) * 3;
        int cond = e[0], prow0 = e[1], end = e[2];

        // ---- stage x: coalesced gather (1KB segments), fragment-swizzled LDS ----
        {
            int pr = prow0 + sr;
            bool valid = pr < end;
            int orow = sidx[valid ? pr : (end - 1)];
            const float* xs = x + (size_t)orow * D_;
            float* xc = out + (size_t)BD + 2 + (size_t)orow * D_;
#pragma unroll 1
            for (int it = 0; it < 4; ++it) {
                int col0 = it * 256 + cg * 8;
                float4 f0 = *(const float4*)(xs + col0);
                float4 f1 = *(const float4*)(xs + col0 + 4);
                int ks = it * 8 + skb;
                *(bf16x8*)(ldsx + ks * 1024 + skg * 256 + ((sr ^ skb) * 16)) = cvt8(f0, f1);
                if (valid) {
                    float2* xo = (float2*)(xc + col0);
                    xo[0] = make_float2(f0.x, f0.y); xo[1] = make_float2(f0.z, f0.w);
                    xo[2] = make_float2(f1.x, f1.y); xo[3] = make_float2(f1.z, f1.w);
                    xsq += f0.x*f0.x + f0.y*f0.y + f0.z*f0.z + f0.w*f0.w
                         + f1.x*f1.x + f1.y*f1.y + f1.z*f1.z + f1.w*f1.w;
                }
            }
        }
        __syncthreads();

        // ---- L1: wave wv computes h cols [wv*16,+16) for 16 rows ----
        const char* bA = (const char*)w1s + (size_t)cond * 262144 + wv * 32768 + lane * 16;
        f32x4 acc = {};
#pragma unroll 4
        for (int ks = 0; ks < 32; ++ks) {
            bf16x8 b  = *(const bf16x8*)(bA + ks * 1024);
            bf16x8 x0 = *(const bf16x8*)(ldsx + ks * 1024 + kg * 256 + ((l15 ^ (ks & 7)) * 16));
            acc = __builtin_amdgcn_mfma_f32_16x16x32_bf16(x0, b, acc, 0, 0, 0);
        }
        __syncthreads();   // all waves done reading x region

        // ---- h + b1 -> Hs (swizzled bf16) ----
        {
            int j0 = wv * 16 + l15;
            float bias = b1f[cond * 128 + j0];
            int sl0 = j0 >> 3, jb = j0 & 7;
#pragma unroll
            for (int v = 0; v < 4; ++v) {
                int r0 = kg * 4 + v;
                __bf16 h0 = (__bf16)(acc[v] + bias);
                Hs[r0 * 128 + ((sl0 ^ (r0 & 7)) * 8) + jb] = __builtin_bit_cast(ushort_t, h0);
            }
        }
        __syncthreads();

        // ---- pa fragments ----
        bf16x8 pa[4];
#pragma unroll
        for (int i = 0; i < 4; ++i)
            pa[i] = *(const bf16x8*)(Hs + l15 * 128 + (((i * 4 + kg) ^ (l15 & 7)) * 8));

        // ---- L2: wave wv owns out cols [wv*128,+128); sequential q->MFMA, low regs ----
        const char* w2b = (const char*)w2s + (size_t)cond * 262144 + wv * 32768 + lane * 16;
        float sq[4] = {0.f, 0.f, 0.f, 0.f};
        unsigned cswz = (unsigned)((kg & 1) << 4);
#pragma unroll 1
        for (int f = 0; f < 8; ++f) {
            const char* wb = w2b + f * 4096;
            f32x4 c0 = {};
            bf16x8 q;
            q  = *(const bf16x8*)(wb);
            c0 = __builtin_amdgcn_mfma_f32_16x16x32_bf16(pa[0], q, c0, 0, 0, 0);
            q  = *(const bf16x8*)(wb + 1024);
            c0 = __builtin_amdgcn_mfma_f32_16x16x32_bf16(pa[1], q, c0, 0, 0, 0);
            q  = *(const bf16x8*)(wb + 2048);
            c0 = __builtin_amdgcn_mfma_f32_16x16x32_bf16(pa[2], q, c0, 0, 0, 0);
            q  = *(const bf16x8*)(wb + 3072);
            c0 = __builtin_amdgcn_mfma_f32_16x16x32_bf16(pa[3], q, c0, 0, 0, 0);
            int jg = (wv * 8 + f) * 16 + l15;
            float bias = b2f[cond * 1024 + jg];
            float t0 = c0[0] + bias, t1 = c0[1] + bias, t2 = c0[2] + bias, t3 = c0[3] + bias;
            sq[0] += t0*t0; sq[1] += t1*t1; sq[2] += t2*t2; sq[3] += t3*t3;
            unsigned jc = (unsigned)jg ^ cswz;
            Ot32[(kg * 2    ) * 1024 + jc] = pack2(t0, t1);
            Ot32[(kg * 2 + 1) * 1024 + jc] = pack2(t2, t3);
        }
        // per-row sums: shfl over l15 -> LDS across waves
#pragma unroll
        for (int v = 0; v < 4; ++v) {
            float s = sq[v];
            s += __shfl_xor(s, 1); s += __shfl_xor(s, 2);
            s += __shfl_xor(s, 4); s += __shfl_xor(s, 8);
            if (l15 == 0) sqs[(kg * 4 + v) * 8 + wv] = s;
        }
        __syncthreads();

        // ---- fused normalize + fully-coalesced store: wave wv -> rows [wv*2,+2) ----
#pragma unroll 1
        for (int rr = 0; rr < 2; ++rr) {
            int r = wv * 2 + rr;
            int pr = prow0 + r;
            if (pr < end) {
                int orow = sidx[pr];
                float s = sqs[r*8+0] + sqs[r*8+1] + sqs[r*8+2] + sqs[r*8+3]
                        + sqs[r*8+4] + sqs[r*8+5] + sqs[r*8+6] + sqs[r*8+7];
                float inv = 1.0f / (sqrtf(s) + 1e-10f);
                int hi = (r & 1) * 16;
                unsigned rswz = (unsigned)(((r >> 2) & 1) << 4);
                const unsigned* base = Ot32 + (r >> 1) * 1024;
                float4* go = (float4*)(out + (size_t)orow * D_);
#pragma unroll
                for (int it = 0; it < 4; ++it) {
                    unsigned cu = (unsigned)(lane * 4 + it * 256) ^ rswz;
                    uint4 u = *(const uint4*)(base + cu);
                    float4 v;
                    v.x = (float)__builtin_bit_cast(__bf16, (ushort_t)(u.x >> hi)) * inv;
                    v.y = (float)__builtin_bit_cast(__bf16, (ushort_t)(u.y >> hi)) * inv;
                    v.z = (float)__builtin_bit_cast(__bf16, (ushort_t)(u.z >> hi)) * inv;
                    v.w = (float)__builtin_bit_cast(__bf16, (ushort_t)(u.w >> hi)) * inv;
                    go[lane + it * 64] = v;
                }
            }
        }
        __syncthreads();   // protect LDS for next subtile
    }

    // ---- ||x||^2 block reduction -> 16 buckets; last block finalizes scalars ----
    float s = xsq;
    s += __shfl_xor(s, 1);  s += __shfl_xor(s, 2);  s += __shfl_xor(s, 4);
    s += __shfl_xor(s, 8);  s += __shfl_xor(s, 16); s += __shfl_xor(s, 32);
    if (lane == 0) sqs[wv] = s;
    __syncthreads();
    if (tid == 0) {
        float t = sqs[0] + sqs[1] + sqs[2] + sqs[3] + sqs[4] + sqs[5] + sqs[6] + sqs[7];
        atomicAdd(&ep[blockIdx.x & 15], t);
        __threadfence();
        int prev = atomicAdd(&wsi[24], 1);
        if (prev == GRID_F - 1) {
            __threadfence();
            float e = 0.0f;
#pragma unroll
            for (int i = 0; i < 16; ++i) e += ep[i];
            out[BD] = 0.0f;
            out[BD + 1] = sqrtf(e);
        }
    }
}

extern "C" void kernel_launch(void* const* d_in, const int* in_sizes, int n_in,
                              void* d_out, int out_size, void* d_ws, size_t ws_size,
                              hipStream_t stream) {
    const float* x  = (const float*)d_in[0];
    const int*   c  = (const int*)d_in[1];
    const float* W1 = (const float*)d_in[2];
    const float* b1 = (const float*)d_in[3];
    const float* W2 = (const float*)d_in[4];
    const float* b2 = (const float*)d_in[5];
    float* out = (float*)d_out;
    char* ws = (char*)d_ws;
    int* wsi = (int*)ws;
    float* ep   = (float*)(ws + 131072);
    __bf16* w1s = (__bf16*)(ws + 262144);
    __bf16* w2s = (__bf16*)(ws + 4456448);

    k_prep<<<257, 256, 0, stream>>>(W1, W2, c, w1s, w2s, wsi, ep);
    k_f<<<GRID_F, 512, 0, stream>>>(x, w1s, w2s, b1, b2, wsi, out, ep);
}